// Round 8
// baseline (291.870 us; speedup 1.0000x reference)
//
#include <hip/hip_runtime.h>

#define B_ 4
#define H_ 16
#define S_ 1024
#define D_ 64
#define NEGV -1000000000.0f

typedef __bf16 bf16x8 __attribute__((ext_vector_type(8)));
typedef __bf16 bf16x4 __attribute__((ext_vector_type(4)));
typedef float f32x4 __attribute__((ext_vector_type(4)));

#define MFMA16(A, B, C) __builtin_amdgcn_mfma_f32_16x16x32_bf16(A, B, C, 0, 0, 0)

// barrier that only orders LDS (keeps global stores/loads in flight)
__device__ __forceinline__ void bar_lds() {
  asm volatile("s_waitcnt lgkmcnt(0)" ::: "memory");
  __builtin_amdgcn_sched_barrier(0);
  __builtin_amdgcn_s_barrier();
  __builtin_amdgcn_sched_barrier(0);
}

__device__ __forceinline__ bf16x8 cvt8(const float* p) {
  float4 x = *(const float4*)p;
  float4 y = *(const float4*)(p + 4);
  bf16x8 f;
  f[0]=(__bf16)x.x; f[1]=(__bf16)x.y; f[2]=(__bf16)x.z; f[3]=(__bf16)x.w;
  f[4]=(__bf16)y.x; f[5]=(__bf16)y.y; f[6]=(__bf16)y.z; f[7]=(__bf16)y.w;
  return f;
}

// ---------------- prep: K->Kb bf16, V->Vt bf16 [B,H,D,S], tk->Tkb bf16 ----------------
__global__ __launch_bounds__(256) void prep_kernel(
    const float* __restrict__ K, const float* __restrict__ V,
    const float* __restrict__ Tk,
    __bf16* __restrict__ Kb, __bf16* __restrict__ Vt, __bf16* __restrict__ Tkb)
{
  int bid = blockIdx.x;            // B*H*16 blocks, each a 64-row s-chunk
  int sc = bid & 15;
  int bh = bid >> 4;
  int tid = threadIdx.x;
  __shared__ float s_v[64][65];

  const float* Kc = K + ((size_t)bh*S_ + sc*64)*D_;
  const float* Vc = V + ((size_t)bh*S_ + sc*64)*D_;
  __bf16* Kbc = Kb + ((size_t)bh*S_ + sc*64)*D_;

  {
    const float4* src = (const float4*)Kc + tid*4;
    float4 a = src[0], b = src[1], c = src[2], d = src[3];
    bf16x8 o0, o1;
    o0[0]=(__bf16)a.x; o0[1]=(__bf16)a.y; o0[2]=(__bf16)a.z; o0[3]=(__bf16)a.w;
    o0[4]=(__bf16)b.x; o0[5]=(__bf16)b.y; o0[6]=(__bf16)b.z; o0[7]=(__bf16)b.w;
    o1[0]=(__bf16)c.x; o1[1]=(__bf16)c.y; o1[2]=(__bf16)c.z; o1[3]=(__bf16)c.w;
    o1[4]=(__bf16)d.x; o1[5]=(__bf16)d.y; o1[6]=(__bf16)d.z; o1[7]=(__bf16)d.w;
    *(bf16x8*)(Kbc + tid*16)     = o0;
    *(bf16x8*)(Kbc + tid*16 + 8) = o1;
  }
  // tk convert: only h==0 blocks (bh multiple of 16 -> b = bh>>4)
  if ((bh & 15) == 0) {
    int b = bh >> 4;
    const float4* src = (const float4*)(Tk + ((size_t)b*S_ + sc*64)*D_) + tid*4;
    __bf16* dst = Tkb + ((size_t)b*S_ + sc*64)*D_ + tid*16;
    float4 a = src[0], bb = src[1], c = src[2], d = src[3];
    bf16x8 o0, o1;
    o0[0]=(__bf16)a.x;  o0[1]=(__bf16)a.y;  o0[2]=(__bf16)a.z;  o0[3]=(__bf16)a.w;
    o0[4]=(__bf16)bb.x; o0[5]=(__bf16)bb.y; o0[6]=(__bf16)bb.z; o0[7]=(__bf16)bb.w;
    o1[0]=(__bf16)c.x;  o1[1]=(__bf16)c.y;  o1[2]=(__bf16)c.z;  o1[3]=(__bf16)c.w;
    o1[4]=(__bf16)d.x;  o1[5]=(__bf16)d.y;  o1[6]=(__bf16)d.z;  o1[7]=(__bf16)d.w;
    *(bf16x8*)dst       = o0;
    *(bf16x8*)(dst + 8) = o1;
  }
  for (int i = tid; i < 64*16; i += 256) {
    int r = i >> 4, c4 = i & 15;
    float4 v = ((const float4*)(Vc + (size_t)r*D_))[c4];
    s_v[r][c4*4+0] = v.x; s_v[r][c4*4+1] = v.y;
    s_v[r][c4*4+2] = v.z; s_v[r][c4*4+3] = v.w;
  }
  __syncthreads();
  {
    int d = tid >> 2, seg = tid & 3;
    bf16x8 o0, o1;
    #pragma unroll
    for (int j = 0; j < 8; ++j) o0[j] = (__bf16)s_v[seg*16 + j][d];
    #pragma unroll
    for (int j = 0; j < 8; ++j) o1[j] = (__bf16)s_v[seg*16 + 8 + j][d];
    __bf16* dst = Vt + ((size_t)bh*D_ + d)*S_ + sc*64 + seg*16;
    *(bf16x8*)dst = o0;
    *(bf16x8*)(dst + 8) = o1;
  }
}

// ---------------- fused attn: topic QK^T+softmax -> main QK^T -> softmax -> pa -> PV ----------------
__global__ __launch_bounds__(256) void attn_kernel(
    const float* __restrict__ Q, const __bf16* __restrict__ Kb,
    const __bf16* __restrict__ Vt, const __bf16* __restrict__ Tkb,
    const float* __restrict__ tq, const int* __restrict__ mask,
    float* __restrict__ out, float* __restrict__ pa)
{
  int bid0 = blockIdx.x;                 // 4096 = 8 * 512
  int bid = (bid0 & 7)*512 + (bid0 >> 3);
  int qt = bid & 63;
  int h  = (bid >> 6) & 15;
  int b  = bid >> 10;
  int tid = threadIdx.x, wave = tid >> 6, lane = tid & 63;
  int l15 = lane & 15, lhi = lane >> 4;

  // s_mem: per-wave f32 transpose scratch (4 x [16][136] = 34816B),
  // later bf16 P [16][1024] swizzled (32768B) for PV.
  __shared__ __align__(16) char s_mem[4*8704];
  __shared__ float2 s_redA[4][16];
  __shared__ float2 s_redB[4][16];

  size_t bh = (size_t)b*H_ + h;
  const __bf16* Kbh = Kb + bh*S_*D_;
  const __bf16* Tkh = Tkb + (size_t)b*S_*D_;
  const int* mb = mask + b*S_;
  int mq = mb[qt*16 + l15];

  // ---- phase 1: topic QK^T (swapped) ----
  f32x4 ts[16];
  {
    bf16x8 tqf[2];
    #pragma unroll
    for (int dc = 0; dc < 2; ++dc)
      tqf[dc] = cvt8(tq + ((size_t)b*S_ + qt*16 + l15)*D_ + dc*32 + lhi*8);
    #pragma unroll
    for (int kt = 0; kt < 16; ++kt) {
      int kb = wave*256 + kt*16;
      const __bf16* tkr = Tkh + (size_t)(kb + l15)*D_ + lhi*8;
      bf16x8 t0 = *(const bf16x8*)tkr;
      bf16x8 t1 = *(const bf16x8*)(tkr + 32);
      f32x4 acc = {0.f,0.f,0.f,0.f};
      acc = MFMA16(t0, tqf[0], acc);
      acc = MFMA16(t1, tqf[1], acc);
      int4 mk = *(const int4*)(mb + kb + lhi*4);
      ts[kt][0] = (mq && mk.x) ? acc[0]*0.125f : 1.0f;
      ts[kt][1] = (mq && mk.y) ? acc[1]*0.125f : 1.0f;
      ts[kt][2] = (mq && mk.z) ? acc[2]*0.125f : 1.0f;
      ts[kt][3] = (mq && mk.w) ? acc[3]*0.125f : 1.0f;
    }
  }
  // topic softmax (in-register, k across lanes lhi groups + 4 waves)
  float scale_t;
  {
    float m = -3.4e38f;
    #pragma unroll
    for (int kt = 0; kt < 16; ++kt)
      #pragma unroll
      for (int i = 0; i < 4; ++i) m = fmaxf(m, ts[kt][i]);
    m = fmaxf(m, __shfl_xor(m, 16));
    m = fmaxf(m, __shfl_xor(m, 32));
    float sum = 0.f;
    #pragma unroll
    for (int kt = 0; kt < 16; ++kt)
      #pragma unroll
      for (int i = 0; i < 4; ++i) { ts[kt][i] = __expf(ts[kt][i] - m); sum += ts[kt][i]; }
    sum += __shfl_xor(sum, 16);
    sum += __shfl_xor(sum, 32);
    if (lane < 16) s_redA[wave][l15] = make_float2(m, sum);
    bar_lds();
    float M = -3.4e38f;
    #pragma unroll
    for (int w = 0; w < 4; ++w) M = fmaxf(M, s_redA[w][l15].x);
    float Z = 0.f;
    #pragma unroll
    for (int w = 0; w < 4; ++w) Z += s_redA[w][l15].y * __expf(s_redA[w][l15].x - M);
    scale_t = __expf(m - M) / Z;
  }

  // ---- phase 2: main QK^T (swapped), fold topic prob + mask in place ----
  {
    bf16x8 qf[2];
    #pragma unroll
    for (int dc = 0; dc < 2; ++dc)
      qf[dc] = cvt8(Q + (bh*S_ + qt*16 + l15)*D_ + dc*32 + lhi*8);
    #pragma unroll
    for (int kt = 0; kt < 16; ++kt) {
      int kb = wave*256 + kt*16;
      const __bf16* kr = Kbh + (size_t)(kb + l15)*D_ + lhi*8;
      bf16x8 k0 = *(const bf16x8*)kr;
      bf16x8 k1 = *(const bf16x8*)(kr + 32);
      f32x4 acc = {0.f,0.f,0.f,0.f};
      acc = MFMA16(k0, qf[0], acc);
      acc = MFMA16(k1, qf[1], acc);
      int4 mk = *(const int4*)(mb + kb + lhi*4);
      float t0 = ts[kt][0]*scale_t, t1 = ts[kt][1]*scale_t;
      float t2 = ts[kt][2]*scale_t, t3 = ts[kt][3]*scale_t;
      ts[kt][0] = (mq && mk.x) ? acc[0]*0.125f*t0 : NEGV*t0;
      ts[kt][1] = (mq && mk.y) ? acc[1]*0.125f*t1 : NEGV*t1;
      ts[kt][2] = (mq && mk.z) ? acc[2]*0.125f*t2 : NEGV*t2;
      ts[kt][3] = (mq && mk.w) ? acc[3]*0.125f*t3 : NEGV*t3;
    }
  }

  // ---- main softmax ----
  float scale;
  float m = -3.4e38f;
  #pragma unroll
  for (int kt = 0; kt < 16; ++kt)
    #pragma unroll
    for (int i = 0; i < 4; ++i) m = fmaxf(m, ts[kt][i]);
  m = fmaxf(m, __shfl_xor(m, 16));
  m = fmaxf(m, __shfl_xor(m, 32));
  float sum = 0.f;
  #pragma unroll
  for (int kt = 0; kt < 16; ++kt)
    #pragma unroll
    for (int i = 0; i < 4; ++i) { ts[kt][i] = __expf(ts[kt][i] - m); sum += ts[kt][i]; }
  sum += __shfl_xor(sum, 16);
  sum += __shfl_xor(sum, 32);
  if (lane < 16) s_redB[wave][l15] = make_float2(m, sum);
  bar_lds();
  float M = -3.4e38f;
  #pragma unroll
  for (int w = 0; w < 4; ++w) M = fmaxf(M, s_redB[w][l15].x);
  float Z = 0.f;
  #pragma unroll
  for (int w = 0; w < 4; ++w) Z += s_redB[w][l15].y * __expf(s_redB[w][l15].x - M);
  scale = __expf(m - M) / Z;

  #pragma unroll
  for (int kt = 0; kt < 16; ++kt)
    #pragma unroll
    for (int i = 0; i < 4; ++i) ts[kt][i] *= scale;

  // ---- pa: transpose via wave-private f32 LDS, coalesced nontemporal f32x4 stores ----
  float* xw = (float*)s_mem + wave*2176;                       // [16][136]
  float* paw = pa + (bh*S_ + qt*16)*S_ + wave*256;
  #pragma unroll
  for (int hh = 0; hh < 2; ++hh) {
    #pragma unroll
    for (int j = 0; j < 8; ++j)
      *(f32x4*)(xw + l15*136 + j*16 + lhi*4) = ts[hh*8 + j];
    bar_lds();
    #pragma unroll
    for (int rr = 0; rr < 8; ++rr) {
      int r = rr*2 + (lane >> 5);
      f32x4 a = *(f32x4*)(xw + r*136 + (lane & 31)*4);
      __builtin_nontemporal_store(a, (f32x4*)(paw + (size_t)r*S_ + hh*128 + (lane & 31)*4));
    }
    bar_lds();
  }

  // ---- P -> bf16 LDS (swizzled) ----
  #pragma unroll
  for (int kt = 0; kt < 16; ++kt) {
    bf16x4 pb;
    pb[0] = (__bf16)ts[kt][0]; pb[1] = (__bf16)ts[kt][1];
    pb[2] = (__bf16)ts[kt][2]; pb[3] = (__bf16)ts[kt][3];
    *(bf16x4*)(s_mem + l15*2048 + ((wave*512 + kt*32 + lhi*8) ^ ((l15 & 7) << 4))) = pb;
  }
  bar_lds();

  // ---- PV: wave w covers d in [w*16, w*16+16); A from LDS, B from global Vt ----
  const __bf16* Vh = Vt + (bh*D_ + wave*16 + l15)*S_ + lhi*8;
  f32x4 oacc = {0.f,0.f,0.f,0.f};
  #pragma unroll
  for (int ks = 0; ks < 32; ++ks) {
    bf16x8 a  = *(const bf16x8*)(s_mem + l15*2048 + ((ks*64 + lhi*16) ^ ((l15 & 7) << 4)));
    bf16x8 bv = *(const bf16x8*)(Vh + ks*32);
    oacc = MFMA16(a, bv, oacc);
  }
  #pragma unroll
  for (int i = 0; i < 4; ++i)
    __builtin_nontemporal_store(oacc[i], out + (bh*S_ + qt*16 + lhi*4 + i)*D_ + wave*16 + l15);
}

extern "C" void kernel_launch(void* const* d_in, const int* in_sizes, int n_in,
                              void* d_out, int out_size, void* d_ws, size_t ws_size,
                              hipStream_t stream) {
  const float* Q    = (const float*)d_in[0];
  const float* K    = (const float*)d_in[1];
  const float* V    = (const float*)d_in[2];
  const int*   mask = (const int*)d_in[4];
  const float* tq   = (const float*)d_in[5];
  const float* tk   = (const float*)d_in[6];

  // ws layout: Kb bf16 [B,H,S,D] = 8MB | Vt bf16 [B,H,D,S] = 8MB | Tkb bf16 [B,S,D] = 2MB
  __bf16* Kb  = (__bf16*)d_ws;
  __bf16* Vt  = Kb + (size_t)B_*H_*S_*D_;
  __bf16* Tkb = Vt + (size_t)B_*H_*S_*D_;

  float* outp = (float*)d_out;                      // [B,H,S,D]
  float* pa   = outp + (size_t)B_*H_*S_*D_;         // [B,H,S,S]

  prep_kernel <<<B_*H_*16, 256, 0, stream>>>(K, V, tk, Kb, Vt, Tkb);
  attn_kernel <<<B_*H_*64, 256, 0, stream>>>(Q, Kb, Vt, Tkb, tq, mask, outp, pa);
}

// Round 9
// 192.637 us; speedup vs baseline: 1.5151x; 1.5151x over previous
//
#include <hip/hip_runtime.h>

#define B_ 4
#define H_ 16
#define S_ 1024
#define D_ 64
#define NEGV -1000000000.0f

typedef __bf16 bf16x8 __attribute__((ext_vector_type(8)));
typedef __bf16 bf16x4 __attribute__((ext_vector_type(4)));
typedef float f32x4 __attribute__((ext_vector_type(4)));

#define MFMA16(A, B, C) __builtin_amdgcn_mfma_f32_16x16x32_bf16(A, B, C, 0, 0, 0)

// barrier that only orders LDS (keeps global stores/loads in flight)
__device__ __forceinline__ void bar_lds() {
  asm volatile("s_waitcnt lgkmcnt(0)" ::: "memory");
  __builtin_amdgcn_sched_barrier(0);
  __builtin_amdgcn_s_barrier();
  __builtin_amdgcn_sched_barrier(0);
}

__device__ __forceinline__ bf16x8 cvt8(const float* p) {
  float4 x = *(const float4*)p;
  float4 y = *(const float4*)(p + 4);
  bf16x8 f;
  f[0]=(__bf16)x.x; f[1]=(__bf16)x.y; f[2]=(__bf16)x.z; f[3]=(__bf16)x.w;
  f[4]=(__bf16)y.x; f[5]=(__bf16)y.y; f[6]=(__bf16)y.z; f[7]=(__bf16)y.w;
  return f;
}

// ---------------- prep: K f32 -> Kb (bf16 [B,H,S,D]), V f32 -> Vt (bf16 [B,H,D,S]) ----------------
__global__ __launch_bounds__(256) void prep_kernel(
    const float* __restrict__ K, const float* __restrict__ V,
    __bf16* __restrict__ Kb, __bf16* __restrict__ Vt)
{
  int bid = blockIdx.x;            // B*H*16 blocks, each a 64-row s-chunk
  int sc = bid & 15;
  int bh = bid >> 4;
  int tid = threadIdx.x;
  __shared__ float s_v[64][65];

  const float* Kc = K + ((size_t)bh*S_ + sc*64)*D_;
  const float* Vc = V + ((size_t)bh*S_ + sc*64)*D_;
  __bf16* Kbc = Kb + ((size_t)bh*S_ + sc*64)*D_;

  {
    const float4* src = (const float4*)Kc + tid*4;
    float4 a = src[0], b = src[1], c = src[2], d = src[3];
    bf16x8 o0, o1;
    o0[0]=(__bf16)a.x; o0[1]=(__bf16)a.y; o0[2]=(__bf16)a.z; o0[3]=(__bf16)a.w;
    o0[4]=(__bf16)b.x; o0[5]=(__bf16)b.y; o0[6]=(__bf16)b.z; o0[7]=(__bf16)b.w;
    o1[0]=(__bf16)c.x; o1[1]=(__bf16)c.y; o1[2]=(__bf16)c.z; o1[3]=(__bf16)c.w;
    o1[4]=(__bf16)d.x; o1[5]=(__bf16)d.y; o1[6]=(__bf16)d.z; o1[7]=(__bf16)d.w;
    *(bf16x8*)(Kbc + tid*16)     = o0;
    *(bf16x8*)(Kbc + tid*16 + 8) = o1;
  }
  for (int i = tid; i < 64*16; i += 256) {
    int r = i >> 4, c4 = i & 15;
    float4 v = ((const float4*)(Vc + (size_t)r*D_))[c4];
    s_v[r][c4*4+0] = v.x; s_v[r][c4*4+1] = v.y;
    s_v[r][c4*4+2] = v.z; s_v[r][c4*4+3] = v.w;
  }
  __syncthreads();
  {
    int d = tid >> 2, seg = tid & 3;
    bf16x8 o0, o1;
    #pragma unroll
    for (int j = 0; j < 8; ++j) o0[j] = (__bf16)s_v[seg*16 + j][d];
    #pragma unroll
    for (int j = 0; j < 8; ++j) o1[j] = (__bf16)s_v[seg*16 + 8 + j][d];
    __bf16* dst = Vt + ((size_t)bh*D_ + d)*S_ + sc*64 + seg*16;
    *(bf16x8*)dst = o0;
    *(bf16x8*)(dst + 8) = o1;
  }
}

// ---------------- topic: swapped MFMA + in-reg softmax -> signed bf16 tp [B,S,S] ----------------
// tp > 0: pair-unmasked, |tp| = topic_prob; tp < 0: pair-masked
__global__ __launch_bounds__(256) void topic_kernel(
    const float* __restrict__ tq, const float* __restrict__ tk,
    const int* __restrict__ mask, __bf16* __restrict__ tp)
{
  int bid0 = blockIdx.x;                 // 256 = 8 * 32
  int bid = (bid0 & 7)*32 + (bid0 >> 3);
  int qt = bid & 63, b = bid >> 6;
  int tid = threadIdx.x, wave = tid >> 6, lane = tid & 63;
  int l15 = lane & 15, lhi = lane >> 4;
  __shared__ float2 s_red[4][16];
  __shared__ __align__(16) char s_mem[4*8704];   // per-wave f32 transpose scratch [16][136]

  const int* mb = mask + b*S_;
  bf16x8 qf[2];
  #pragma unroll
  for (int dc = 0; dc < 2; ++dc)
    qf[dc] = cvt8(tq + ((size_t)b*S_ + qt*16 + l15)*D_ + dc*32 + lhi*8);
  int mq = mb[qt*16 + l15];

  f32x4 sc[16];
  #pragma unroll
  for (int kt = 0; kt < 16; ++kt) {
    int kb = wave*256 + kt*16;
    const float* kr = tk + ((size_t)b*S_ + kb + l15)*D_ + lhi*8;
    bf16x8 k0 = cvt8(kr);
    bf16x8 k1 = cvt8(kr + 32);
    f32x4 acc = {0.f,0.f,0.f,0.f};
    acc = MFMA16(k0, qf[0], acc);
    acc = MFMA16(k1, qf[1], acc);
    int4 mk = *(const int4*)(mb + kb + lhi*4);
    sc[kt][0] = (mq && mk.x) ? acc[0]*0.125f : 1.0f;
    sc[kt][1] = (mq && mk.y) ? acc[1]*0.125f : 1.0f;
    sc[kt][2] = (mq && mk.z) ? acc[2]*0.125f : 1.0f;
    sc[kt][3] = (mq && mk.w) ? acc[3]*0.125f : 1.0f;
  }
  float m = -3.4e38f;
  #pragma unroll
  for (int kt = 0; kt < 16; ++kt)
    #pragma unroll
    for (int i = 0; i < 4; ++i) m = fmaxf(m, sc[kt][i]);
  m = fmaxf(m, __shfl_xor(m, 16));
  m = fmaxf(m, __shfl_xor(m, 32));
  float sum = 0.f;
  #pragma unroll
  for (int kt = 0; kt < 16; ++kt)
    #pragma unroll
    for (int i = 0; i < 4; ++i) { sc[kt][i] = __expf(sc[kt][i] - m); sum += sc[kt][i]; }
  sum += __shfl_xor(sum, 16);
  sum += __shfl_xor(sum, 32);
  if (lane < 16) s_red[wave][l15] = make_float2(m, sum);
  bar_lds();
  float M = -3.4e38f;
  #pragma unroll
  for (int w = 0; w < 4; ++w) M = fmaxf(M, s_red[w][l15].x);
  float Z = 0.f;
  #pragma unroll
  for (int w = 0; w < 4; ++w) Z += s_red[w][l15].y * __expf(s_red[w][l15].x - M);
  float scale = __expf(m - M) / Z;

  // apply scale + mask sign in registers
  #pragma unroll
  for (int kt = 0; kt < 16; ++kt) {
    int kb = wave*256 + kt*16;
    int4 mk = *(const int4*)(mb + kb + lhi*4);
    sc[kt][0] *= scale; if (!(mq && mk.x)) sc[kt][0] = -sc[kt][0];
    sc[kt][1] *= scale; if (!(mq && mk.y)) sc[kt][1] = -sc[kt][1];
    sc[kt][2] *= scale; if (!(mq && mk.z)) sc[kt][2] = -sc[kt][2];
    sc[kt][3] *= scale; if (!(mq && mk.w)) sc[kt][3] = -sc[kt][3];
  }

  // transpose via wave-private LDS -> coalesced bf16 stores
  float* xw = (float*)s_mem + wave*2176;
  __bf16* tpw = tp + ((size_t)b*S_ + qt*16)*S_ + wave*256;
  #pragma unroll
  for (int h = 0; h < 2; ++h) {
    #pragma unroll
    for (int j = 0; j < 8; ++j)
      *(f32x4*)(xw + l15*136 + j*16 + lhi*4) = sc[h*8 + j];
    bar_lds();
    #pragma unroll
    for (int rr = 0; rr < 8; ++rr) {
      int r = rr*2 + (lane >> 5);
      f32x4 a = *(f32x4*)(xw + r*136 + (lane & 31)*4);
      bf16x4 o;
      o[0]=(__bf16)a[0]; o[1]=(__bf16)a[1]; o[2]=(__bf16)a[2]; o[3]=(__bf16)a[3];
      *(bf16x4*)(tpw + (size_t)r*S_ + h*128 + (lane & 31)*4) = o;
    }
    bar_lds();
  }
}

// ---------------- attn: swapped QK^T (ring) -> in-reg softmax -> coalesced pa -> PV (ring) ----------------
__global__ __launch_bounds__(256) void attn_kernel(
    const float* __restrict__ Q, const __bf16* __restrict__ Kb,
    const __bf16* __restrict__ Vt, const __bf16* __restrict__ tp,
    float* __restrict__ out, float* __restrict__ pa)
{
  int bid0 = blockIdx.x;                 // 4096 = 8 * 512
  int bid = (bid0 & 7)*512 + (bid0 >> 3);
  int qt = bid & 63;
  int h  = (bid >> 6) & 15;
  int b  = bid >> 10;
  int tid = threadIdx.x, wave = tid >> 6, lane = tid & 63;
  int l15 = lane & 15, lhi = lane >> 4;

  // s_mem: per-wave f32 transpose scratch (4 x [16][136] = 34816B),
  // later bf16 P [16][1024] swizzled (32768B) for PV.
  __shared__ __align__(16) char s_mem[4*8704];
  __shared__ float2 s_red[4][16];

  size_t bh = (size_t)b*H_ + h;
  const __bf16* Kbh = Kb + bh*S_*D_;
  const __bf16* tpb = tp + ((size_t)b*S_ + qt*16 + l15)*S_;   // this lane's q-row

  bf16x8 qf[2];
  #pragma unroll
  for (int dc = 0; dc < 2; ++dc)
    qf[dc] = cvt8(Q + (bh*S_ + qt*16 + l15)*D_ + dc*32 + lhi*8);

  // ---- QK^T swapped, depth-2 register prefetch ring ----
  f32x4 sc[16];
  bf16x8 rk0[3], rk1[3];
  bf16x4 rt[3];
  #pragma unroll
  for (int p = 0; p < 2; ++p) {
    int kb = wave*256 + p*16;
    const __bf16* kr = Kbh + (size_t)(kb + l15)*D_ + lhi*8;
    rk0[p] = *(const bf16x8*)kr;
    rk1[p] = *(const bf16x8*)(kr + 32);
    rt[p]  = *(const bf16x4*)(tpb + kb + lhi*4);
  }
  #pragma unroll
  for (int kt = 0; kt < 16; ++kt) {
    const int cur = kt % 3;
    if (kt + 2 < 16) {
      const int nxt = (kt + 2) % 3;
      int kb = wave*256 + (kt+2)*16;
      const __bf16* kr = Kbh + (size_t)(kb + l15)*D_ + lhi*8;
      rk0[nxt] = *(const bf16x8*)kr;
      rk1[nxt] = *(const bf16x8*)(kr + 32);
      rt[nxt]  = *(const bf16x4*)(tpb + kb + lhi*4);
    }
    f32x4 acc = {0.f,0.f,0.f,0.f};
    acc = MFMA16(rk0[cur], qf[0], acc);
    acc = MFMA16(rk1[cur], qf[1], acc);
    #pragma unroll
    for (int i = 0; i < 4; ++i) {
      float t = (float)rt[cur][i];
      sc[kt][i] = (t > 0.f) ? acc[i]*0.125f*t : NEGV*(-t);
    }
  }

  // ---- in-register softmax over k ----
  float m = -3.4e38f;
  #pragma unroll
  for (int kt = 0; kt < 16; ++kt)
    #pragma unroll
    for (int i = 0; i < 4; ++i) m = fmaxf(m, sc[kt][i]);
  m = fmaxf(m, __shfl_xor(m, 16));
  m = fmaxf(m, __shfl_xor(m, 32));
  float sum = 0.f;
  #pragma unroll
  for (int kt = 0; kt < 16; ++kt)
    #pragma unroll
    for (int i = 0; i < 4; ++i) { sc[kt][i] = __expf(sc[kt][i] - m); sum += sc[kt][i]; }
  sum += __shfl_xor(sum, 16);
  sum += __shfl_xor(sum, 32);
  if (lane < 16) s_red[wave][l15] = make_float2(m, sum);
  bar_lds();
  float M = -3.4e38f;
  #pragma unroll
  for (int w = 0; w < 4; ++w) M = fmaxf(M, s_red[w][l15].x);
  float Z = 0.f;
  #pragma unroll
  for (int w = 0; w < 4; ++w) Z += s_red[w][l15].y * __expf(s_red[w][l15].x - M);
  float scale = __expf(m - M) / Z;

  #pragma unroll
  for (int kt = 0; kt < 16; ++kt)
    #pragma unroll
    for (int i = 0; i < 4; ++i) sc[kt][i] *= scale;

  // ---- pa: transpose via wave-private f32 LDS, coalesced nontemporal f32x4 stores ----
  float* xw = (float*)s_mem + wave*2176;                       // [16][136]
  float* paw = pa + (bh*S_ + qt*16)*S_ + wave*256;
  #pragma unroll
  for (int hh = 0; hh < 2; ++hh) {
    #pragma unroll
    for (int j = 0; j < 8; ++j)
      *(f32x4*)(xw + l15*136 + j*16 + lhi*4) = sc[hh*8 + j];
    bar_lds();
    #pragma unroll
    for (int rr = 0; rr < 8; ++rr) {
      int r = rr*2 + (lane >> 5);
      f32x4 a = *(f32x4*)(xw + r*136 + (lane & 31)*4);
      __builtin_nontemporal_store(a, (f32x4*)(paw + (size_t)r*S_ + hh*128 + (lane & 31)*4));
    }
    bar_lds();
  }

  // ---- P -> bf16 LDS (swizzled) ----
  #pragma unroll
  for (int kt = 0; kt < 16; ++kt) {
    bf16x4 pb;
    pb[0] = (__bf16)sc[kt][0]; pb[1] = (__bf16)sc[kt][1];
    pb[2] = (__bf16)sc[kt][2]; pb[3] = (__bf16)sc[kt][3];
    *(bf16x4*)(s_mem + l15*2048 + ((wave*512 + kt*32 + lhi*8) ^ ((l15 & 7) << 4))) = pb;
  }
  bar_lds();

  // ---- PV: wave w covers d in [w*16, w*16+16); A from LDS, B from global Vt (ring) ----
  const __bf16* Vh = Vt + (bh*D_ + wave*16 + l15)*S_ + lhi*8;
  bf16x8 rv[3];
  #pragma unroll
  for (int p = 0; p < 2; ++p) rv[p] = *(const bf16x8*)(Vh + p*32);
  f32x4 oacc = {0.f,0.f,0.f,0.f};
  #pragma unroll
  for (int ks = 0; ks < 32; ++ks) {
    if (ks + 2 < 32) rv[(ks+2)%3] = *(const bf16x8*)(Vh + (ks+2)*32);
    bf16x8 a = *(const bf16x8*)(s_mem + l15*2048 + ((ks*64 + lhi*16) ^ ((l15 & 7) << 4)));
    oacc = MFMA16(a, rv[ks%3], oacc);
  }
  #pragma unroll
  for (int i = 0; i < 4; ++i)
    __builtin_nontemporal_store(oacc[i], out + (bh*S_ + qt*16 + lhi*4 + i)*D_ + wave*16 + l15);
}

extern "C" void kernel_launch(void* const* d_in, const int* in_sizes, int n_in,
                              void* d_out, int out_size, void* d_ws, size_t ws_size,
                              hipStream_t stream) {
  const float* Q    = (const float*)d_in[0];
  const float* K    = (const float*)d_in[1];
  const float* V    = (const float*)d_in[2];
  const int*   mask = (const int*)d_in[4];
  const float* tq   = (const float*)d_in[5];
  const float* tk   = (const float*)d_in[6];

  // ws layout: tp bf16 [B,S,S] = 8MB | Kb bf16 [B,H,S,D] = 8MB | Vt bf16 [B,H,D,S] = 8MB
  __bf16* tp = (__bf16*)d_ws;
  __bf16* Kb = tp + (size_t)B_*S_*S_;
  __bf16* Vt = Kb + (size_t)B_*H_*S_*D_;

  float* outp = (float*)d_out;                      // [B,H,S,D]
  float* pa   = outp + (size_t)B_*H_*S_*D_;         // [B,H,S,S]

  prep_kernel <<<B_*H_*16, 256, 0, stream>>>(K, V, Kb, Vt);
  topic_kernel<<<B_*64,    256, 0, stream>>>(tq, tk, mask, tp);
  attn_kernel <<<B_*H_*64, 256, 0, stream>>>(Q, Kb, Vt, tp, outp, pa);
}

// Round 10
// 189.941 us; speedup vs baseline: 1.5366x; 1.0142x over previous
//
#include <hip/hip_runtime.h>

#define B_ 4
#define H_ 16
#define S_ 1024
#define D_ 64
#define NEGV -1000000000.0f

typedef __bf16 bf16x8 __attribute__((ext_vector_type(8)));
typedef __bf16 bf16x4 __attribute__((ext_vector_type(4)));
typedef float f32x4 __attribute__((ext_vector_type(4)));

#define MFMA16(A, B, C) __builtin_amdgcn_mfma_f32_16x16x32_bf16(A, B, C, 0, 0, 0)

// barrier that only orders LDS (keeps global stores/loads in flight)
__device__ __forceinline__ void bar_lds() {
  asm volatile("s_waitcnt lgkmcnt(0)" ::: "memory");
  __builtin_amdgcn_sched_barrier(0);
  __builtin_amdgcn_s_barrier();
  __builtin_amdgcn_sched_barrier(0);
}

__device__ __forceinline__ bf16x8 cvt8(const float* p) {
  float4 x = *(const float4*)p;
  float4 y = *(const float4*)(p + 4);
  bf16x8 f;
  f[0]=(__bf16)x.x; f[1]=(__bf16)x.y; f[2]=(__bf16)x.z; f[3]=(__bf16)x.w;
  f[4]=(__bf16)y.x; f[5]=(__bf16)y.y; f[6]=(__bf16)y.z; f[7]=(__bf16)y.w;
  return f;
}

// ---------------- prep: K f32 -> Kb (bf16 [B,H,S,D]), V f32 -> Vt (bf16 [B,H,D,S]) ----------------
__global__ __launch_bounds__(256) void prep_kernel(
    const float* __restrict__ K, const float* __restrict__ V,
    __bf16* __restrict__ Kb, __bf16* __restrict__ Vt)
{
  int bid = blockIdx.x;            // B*H*16 blocks, each a 64-row s-chunk
  int sc = bid & 15;
  int bh = bid >> 4;
  int tid = threadIdx.x;
  __shared__ float s_v[64][65];

  const float* Kc = K + ((size_t)bh*S_ + sc*64)*D_;
  const float* Vc = V + ((size_t)bh*S_ + sc*64)*D_;
  __bf16* Kbc = Kb + ((size_t)bh*S_ + sc*64)*D_;

  {
    const float4* src = (const float4*)Kc + tid*4;
    float4 a = src[0], b = src[1], c = src[2], d = src[3];
    bf16x8 o0, o1;
    o0[0]=(__bf16)a.x; o0[1]=(__bf16)a.y; o0[2]=(__bf16)a.z; o0[3]=(__bf16)a.w;
    o0[4]=(__bf16)b.x; o0[5]=(__bf16)b.y; o0[6]=(__bf16)b.z; o0[7]=(__bf16)b.w;
    o1[0]=(__bf16)c.x; o1[1]=(__bf16)c.y; o1[2]=(__bf16)c.z; o1[3]=(__bf16)c.w;
    o1[4]=(__bf16)d.x; o1[5]=(__bf16)d.y; o1[6]=(__bf16)d.z; o1[7]=(__bf16)d.w;
    *(bf16x8*)(Kbc + tid*16)     = o0;
    *(bf16x8*)(Kbc + tid*16 + 8) = o1;
  }
  for (int i = tid; i < 64*16; i += 256) {
    int r = i >> 4, c4 = i & 15;
    float4 v = ((const float4*)(Vc + (size_t)r*D_))[c4];
    s_v[r][c4*4+0] = v.x; s_v[r][c4*4+1] = v.y;
    s_v[r][c4*4+2] = v.z; s_v[r][c4*4+3] = v.w;
  }
  __syncthreads();
  {
    int d = tid >> 2, seg = tid & 3;
    bf16x8 o0, o1;
    #pragma unroll
    for (int j = 0; j < 8; ++j) o0[j] = (__bf16)s_v[seg*16 + j][d];
    #pragma unroll
    for (int j = 0; j < 8; ++j) o1[j] = (__bf16)s_v[seg*16 + 8 + j][d];
    __bf16* dst = Vt + ((size_t)bh*D_ + d)*S_ + sc*64 + seg*16;
    *(bf16x8*)dst = o0;
    *(bf16x8*)(dst + 8) = o1;
  }
}

// ---------------- topic: swapped MFMA + in-reg softmax -> signed bf16 tp [B,S,S] ----------------
__global__ __launch_bounds__(256) void topic_kernel(
    const float* __restrict__ tq, const float* __restrict__ tk,
    const int* __restrict__ mask, __bf16* __restrict__ tp)
{
  int bid0 = blockIdx.x;                 // 256 = 8 * 32
  int bid = (bid0 & 7)*32 + (bid0 >> 3);
  int qt = bid & 63, b = bid >> 6;
  int tid = threadIdx.x, wave = tid >> 6, lane = tid & 63;
  int l15 = lane & 15, lhi = lane >> 4;
  __shared__ float2 s_red[4][16];
  __shared__ __align__(16) char s_mem[4*8704];   // per-wave f32 transpose scratch [16][136]

  const int* mb = mask + b*S_;
  bf16x8 qf[2];
  #pragma unroll
  for (int dc = 0; dc < 2; ++dc)
    qf[dc] = cvt8(tq + ((size_t)b*S_ + qt*16 + l15)*D_ + dc*32 + lhi*8);
  int mq = mb[qt*16 + l15];

  f32x4 sc[16];
  #pragma unroll
  for (int kt = 0; kt < 16; ++kt) {
    int kb = wave*256 + kt*16;
    const float* kr = tk + ((size_t)b*S_ + kb + l15)*D_ + lhi*8;
    bf16x8 k0 = cvt8(kr);
    bf16x8 k1 = cvt8(kr + 32);
    f32x4 acc = {0.f,0.f,0.f,0.f};
    acc = MFMA16(k0, qf[0], acc);
    acc = MFMA16(k1, qf[1], acc);
    int4 mk = *(const int4*)(mb + kb + lhi*4);
    sc[kt][0] = (mq && mk.x) ? acc[0]*0.125f : 1.0f;
    sc[kt][1] = (mq && mk.y) ? acc[1]*0.125f : 1.0f;
    sc[kt][2] = (mq && mk.z) ? acc[2]*0.125f : 1.0f;
    sc[kt][3] = (mq && mk.w) ? acc[3]*0.125f : 1.0f;
  }
  float m = -3.4e38f;
  #pragma unroll
  for (int kt = 0; kt < 16; ++kt)
    #pragma unroll
    for (int i = 0; i < 4; ++i) m = fmaxf(m, sc[kt][i]);
  m = fmaxf(m, __shfl_xor(m, 16));
  m = fmaxf(m, __shfl_xor(m, 32));
  float sum = 0.f;
  #pragma unroll
  for (int kt = 0; kt < 16; ++kt)
    #pragma unroll
    for (int i = 0; i < 4; ++i) { sc[kt][i] = __expf(sc[kt][i] - m); sum += sc[kt][i]; }
  sum += __shfl_xor(sum, 16);
  sum += __shfl_xor(sum, 32);
  if (lane < 16) s_red[wave][l15] = make_float2(m, sum);
  bar_lds();
  float M = -3.4e38f;
  #pragma unroll
  for (int w = 0; w < 4; ++w) M = fmaxf(M, s_red[w][l15].x);
  float Z = 0.f;
  #pragma unroll
  for (int w = 0; w < 4; ++w) Z += s_red[w][l15].y * __expf(s_red[w][l15].x - M);
  float scale = __expf(m - M) / Z;

  #pragma unroll
  for (int kt = 0; kt < 16; ++kt) {
    int kb = wave*256 + kt*16;
    int4 mk = *(const int4*)(mb + kb + lhi*4);
    sc[kt][0] *= scale; if (!(mq && mk.x)) sc[kt][0] = -sc[kt][0];
    sc[kt][1] *= scale; if (!(mq && mk.y)) sc[kt][1] = -sc[kt][1];
    sc[kt][2] *= scale; if (!(mq && mk.z)) sc[kt][2] = -sc[kt][2];
    sc[kt][3] *= scale; if (!(mq && mk.w)) sc[kt][3] = -sc[kt][3];
  }

  // transpose via wave-private LDS -> coalesced bf16 stores
  float* xw = (float*)s_mem + wave*2176;
  __bf16* tpw = tp + ((size_t)b*S_ + qt*16)*S_ + wave*256;
  #pragma unroll
  for (int h = 0; h < 2; ++h) {
    #pragma unroll
    for (int j = 0; j < 8; ++j)
      *(f32x4*)(xw + l15*136 + j*16 + lhi*4) = sc[h*8 + j];
    bar_lds();
    #pragma unroll
    for (int rr = 0; rr < 8; ++rr) {
      int r = rr*2 + (lane >> 5);
      f32x4 a = *(f32x4*)(xw + r*136 + (lane & 31)*4);
      bf16x4 o;
      o[0]=(__bf16)a[0]; o[1]=(__bf16)a[1]; o[2]=(__bf16)a[2]; o[3]=(__bf16)a[3];
      *(bf16x4*)(tpw + (size_t)r*S_ + h*128 + (lane & 31)*4) = o;
    }
    bar_lds();
  }
}

// ---------------- attn: swapped QK^T -> bf16 score regs -> softmax -> pa (4-pass) -> PV (2 halves) ----------------
__global__ __launch_bounds__(256) void attn_kernel(
    const float* __restrict__ Q, const __bf16* __restrict__ Kb,
    const __bf16* __restrict__ Vt, const __bf16* __restrict__ tp,
    float* __restrict__ out, float* __restrict__ pa)
{
  int bid0 = blockIdx.x;                 // 4096 = 8 * 512
  int bid = (bid0 & 7)*512 + (bid0 >> 3);
  int qt = bid & 63;
  int h  = (bid >> 6) & 15;
  int b  = bid >> 10;
  int tid = threadIdx.x, wave = tid >> 6, lane = tid & 63;
  int l15 = lane & 15, lhi = lane >> 4;

  // s_mem union: (a) per-wave f32 pa scratch 4 x [16][68] f32 = 17408 B
  //              (b) bf16 P half [16][512] swizzled = 16384 B
  __shared__ __align__(16) char s_mem[17408];
  __shared__ float2 s_red[4][16];

  size_t bh = (size_t)b*H_ + h;
  const __bf16* Kbh = Kb + bh*S_*D_;
  const __bf16* tpb = tp + ((size_t)b*S_ + qt*16 + l15)*S_;   // this lane's q-row

  bf16x8 qf[2];
  #pragma unroll
  for (int dc = 0; dc < 2; ++dc)
    qf[dc] = cvt8(Q + (bh*S_ + qt*16 + l15)*D_ + dc*32 + lhi*8);

  // ---- QK^T swapped, double-buffered loads; scores kept as bf16x4 (32 VGPRs) ----
  bf16x4 sb[16];
  bf16x8 rk0[2], rk1[2];
  bf16x4 rt[2];
  {
    const __bf16* kr = Kbh + (size_t)(wave*256 + l15)*D_ + lhi*8;
    rk0[0] = *(const bf16x8*)kr;
    rk1[0] = *(const bf16x8*)(kr + 32);
    rt[0]  = *(const bf16x4*)(tpb + wave*256 + lhi*4);
  }
  #pragma unroll
  for (int kt = 0; kt < 16; ++kt) {
    const int cur = kt & 1;
    if (kt < 15) {
      const int nxt = cur ^ 1;
      int kb = wave*256 + (kt+1)*16;
      const __bf16* kr = Kbh + (size_t)(kb + l15)*D_ + lhi*8;
      rk0[nxt] = *(const bf16x8*)kr;
      rk1[nxt] = *(const bf16x8*)(kr + 32);
      rt[nxt]  = *(const bf16x4*)(tpb + kb + lhi*4);
    }
    f32x4 acc = {0.f,0.f,0.f,0.f};
    acc = MFMA16(rk0[cur], qf[0], acc);
    acc = MFMA16(rk1[cur], qf[1], acc);
    #pragma unroll
    for (int i = 0; i < 4; ++i) {
      float t = (float)rt[cur][i];
      float s = (t > 0.f) ? acc[i]*0.125f*t : NEGV*(-t);
      sb[kt][i] = (__bf16)s;
    }
  }

  // ---- softmax over k (from bf16-rounded scores) ----
  float m = -3.4e38f;
  #pragma unroll
  for (int kt = 0; kt < 16; ++kt)
    #pragma unroll
    for (int i = 0; i < 4; ++i) m = fmaxf(m, (float)sb[kt][i]);
  m = fmaxf(m, __shfl_xor(m, 16));
  m = fmaxf(m, __shfl_xor(m, 32));
  float sum = 0.f;
  #pragma unroll
  for (int kt = 0; kt < 16; ++kt)
    #pragma unroll
    for (int i = 0; i < 4; ++i) sum += __expf((float)sb[kt][i] - m);
  sum += __shfl_xor(sum, 16);
  sum += __shfl_xor(sum, 32);
  if (lane < 16) s_red[wave][l15] = make_float2(m, sum);
  bar_lds();
  float M = -3.4e38f;
  #pragma unroll
  for (int w = 0; w < 4; ++w) M = fmaxf(M, s_red[w][l15].x);
  float Z = 0.f;
  #pragma unroll
  for (int w = 0; w < 4; ++w) Z += s_red[w][l15].y * __expf(s_red[w][l15].x - M);
  const float scale = __expf(m - M) / Z;
  bar_lds();   // s_red consumed; s_mem free for scratch

  // ---- pa: 4 passes, wave-private [16][68] f32 scratch, coalesced nt f32x4 stores ----
  float* xw = (float*)s_mem + wave*4352/4;                     // [16][68] f32
  float* paw = pa + (bh*S_ + qt*16)*S_ + wave*256;
  #pragma unroll
  for (int hh = 0; hh < 4; ++hh) {
    #pragma unroll
    for (int j = 0; j < 4; ++j) {
      int kt = hh*4 + j;
      f32x4 pv;
      #pragma unroll
      for (int i = 0; i < 4; ++i) pv[i] = __expf((float)sb[kt][i] - m) * scale;
      *(f32x4*)(xw + l15*68 + j*16 + lhi*4) = pv;
    }
    bar_lds();
    #pragma unroll
    for (int rr = 0; rr < 4; ++rr) {
      int r = rr*4 + lhi;
      f32x4 a = *(f32x4*)(xw + r*68 + l15*4);
      __builtin_nontemporal_store(a, (f32x4*)(paw + (size_t)r*S_ + hh*64 + l15*4));
    }
    bar_lds();
  }

  // ---- PV in two k-halves: P-half [16][512] bf16 swizzled (16KB), A from LDS, B from Vt ----
  const __bf16* Vh = Vt + (bh*D_ + wave*16 + l15)*S_ + lhi*8;
  f32x4 oacc = {0.f,0.f,0.f,0.f};
  #pragma unroll
  for (int h2 = 0; h2 < 2; ++h2) {
    if ((wave >> 1) == h2) {
      int cb = (wave & 1)*256;               // column base within half
      #pragma unroll
      for (int kt = 0; kt < 16; ++kt) {
        bf16x4 pb;
        #pragma unroll
        for (int i = 0; i < 4; ++i) pb[i] = (__bf16)(__expf((float)sb[kt][i] - m) * scale);
        int col = cb + kt*16 + lhi*4;
        *(bf16x4*)(s_mem + l15*1024 + ((col*2) ^ ((l15 & 7) << 4))) = pb;
      }
    }
    bar_lds();
    #pragma unroll
    for (int ks = 0; ks < 16; ++ks) {
      bf16x8 a  = *(const bf16x8*)(s_mem + l15*1024 + ((ks*64 + lhi*16) ^ ((l15 & 7) << 4)));
      bf16x8 bv = *(const bf16x8*)(Vh + h2*512 + ks*32);
      oacc = MFMA16(a, bv, oacc);
    }
    bar_lds();
  }
  #pragma unroll
  for (int i = 0; i < 4; ++i)
    __builtin_nontemporal_store(oacc[i], out + (bh*S_ + qt*16 + lhi*4 + i)*D_ + wave*16 + l15);
}

extern "C" void kernel_launch(void* const* d_in, const int* in_sizes, int n_in,
                              void* d_out, int out_size, void* d_ws, size_t ws_size,
                              hipStream_t stream) {
  const float* Q    = (const float*)d_in[0];
  const float* K    = (const float*)d_in[1];
  const float* V    = (const float*)d_in[2];
  const int*   mask = (const int*)d_in[4];
  const float* tq   = (const float*)d_in[5];
  const float* tk   = (const float*)d_in[6];

  // ws layout: tp bf16 [B,S,S] = 8MB | Kb bf16 [B,H,S,D] = 8MB | Vt bf16 [B,H,D,S] = 8MB
  __bf16* tp = (__bf16*)d_ws;
  __bf16* Kb = tp + (size_t)B_*S_*S_;
  __bf16* Vt = Kb + (size_t)B_*H_*S_*D_;

  float* outp = (float*)d_out;                      // [B,H,S,D]
  float* pa   = outp + (size_t)B_*H_*S_*D_;         // [B,H,S,S]

  prep_kernel <<<B_*H_*16, 256, 0, stream>>>(K, V, Kb, Vt);
  topic_kernel<<<B_*64,    256, 0, stream>>>(tq, tk, mask, tp);
  attn_kernel <<<B_*H_*64, 256, 0, stream>>>(Q, Kb, Vt, tp, outp, pa);
}